// Round 5
// baseline (273.560 us; speedup 1.0000x reference)
//
#include <hip/hip_runtime.h>
#include <hip/hip_bf16.h>

#define BB 64
#define LL 800
#define DD 100
#define NFC 50
#define MPAD 832
#define DPAD 128

typedef __attribute__((ext_vector_type(8))) short short8;
typedef __attribute__((ext_vector_type(4))) float f32x4;
#define MFMA16(a, b, c) __builtin_amdgcn_mfma_f32_16x16x32_bf16(a, b, c, 0, 0, 0)

struct ConvP {
  const float* w[8];
  const float* bias[8];
};

__device__ __forceinline__ ushort f2bf(float f) {
  unsigned u = __float_as_uint(f);
  u += 0x7fff + ((u >> 16) & 1);
  return (ushort)(u >> 16);
}
__device__ __forceinline__ float bf2f(short s) {
  return __uint_as_float(((unsigned)(ushort)s) << 16);
}
__device__ __forceinline__ unsigned cvtpk(float lo, float hi) {
  unsigned d;
  asm("v_cvt_pk_bf16_f32 %0, %1, %2" : "=v"(d) : "v"(lo), "v"(hi));
  return d;
}
// 4x4 dword transpose across lane groups {c, c+16, c+32, c+48}:
// after swap3216(x0,x2): x0 = rows[X0(0),X0(2),X2(0),X2(2)], x2 = [X0(1),X0(3),X2(1),X2(3)]
__device__ __forceinline__ void swap3216(unsigned& a, unsigned& b) {
  asm("v_permlane32_swap_b32 %0, %1\n\t"
      "v_permlane16_swap_b32 %0, %1"
      : "+v"(a), "+v"(b));
}

// ---- fused gather + bf16 prep ----
// xeb[b][832][128]  : raw bf16 rows (scores A/B, conv br0, residual)
// xeT[b][128][832]  : transposed, MASKED (d<100: x*mask; d=100: mask; d=101: 1; else 0)
__global__ __launch_bounds__(256) void k_prep(const int* __restrict__ x,
                                              const float* __restrict__ emb,
                                              const int* __restrict__ mask,
                                              short* __restrict__ xeb,
                                              short* __restrict__ xeT) {
  __shared__ float tile[64][129];
  __shared__ int toks[64];
  __shared__ float msk[64];
  int bid = blockIdx.x;
  int xcd = bid & 7, slot = bid >> 3;  // same XCD mapping as k_attn
  int b = xcd + 8 * (slot / 13);
  int mt = slot % 13;
  int m0 = mt * 64;
  int t = threadIdx.x;
  if (t < 64) {
    int gm = m0 + t;
    toks[t] = (gm < LL) ? x[b * LL + gm] : 1;
    msk[t] = (gm < LL) ? (float)mask[b * LL + gm] : 0.f;
  }
  __syncthreads();
  for (int i = t; i < 64 * 128; i += 256) {
    int m = i >> 7, d = i & 127;
    int gm = m0 + m;
    float v = 0.f;
    if (gm < LL && d < DD) v = emb[(size_t)toks[m] * DD + d];
    tile[m][d] = v;
    xeb[((size_t)b * MPAD + gm) * DPAD + d] = (short)f2bf(v);
  }
  __syncthreads();
  for (int i = t; i < 64 * 128; i += 256) {
    int m = i & 63, d = i >> 6;
    float mk = msk[m];
    float v;
    if (d < DD) v = tile[m][d] * mk;
    else if (d == DD) v = mk;
    else if (d == DD + 1) v = (m0 + m < LL) ? 1.f : 0.f;
    else v = 0.f;
    xeT[((size_t)b * DPAD + d) * MPAD + m0 + m] = (short)f2bf(v);
  }
}

// ---- bf16 weight pack: wb[br][sz][nf(64)][i(5)][d(128)] zero-padded ----
__global__ __launch_bounds__(256) void k_wprep(ConvP P, short* __restrict__ wb) {
  int idx = blockIdx.x * 256 + threadIdx.x;
  if (idx >= 2 * 4 * 64 * 5 * 128) return;
  int d = idx & 127;
  int r = idx >> 7;
  int i = r % 5; r /= 5;
  int nf = r & 63; r >>= 6;
  int sz = r & 3;
  int br = r >> 2;
  int s = (sz < 3) ? sz + 1 : 5;
  float v = 0.f;
  if (nf < NFC && i < s && d < DD) v = P.w[br * 4 + sz][(nf * s + i) * DD + d];
  wb[idx] = (short)f2bf(v);
}

// ---- MFMA attention: all-register flash loop, no LDS, no barriers ----
// P redistribution via permlane swaps; Z/S2 ride the PV matmul as cols 101/100.
__global__ __launch_bounds__(256, 3) void k_attn(const short* __restrict__ xeb,
                                                 const short* __restrict__ xeT,
                                                 const int* __restrict__ mask,
                                                 short* __restrict__ xhb) {
  int bid = blockIdx.x;
  int xcd = bid & 7, slot = bid >> 3;  // batch -> XCD: panels stay L2-local
  int b = xcd + 8 * (slot / 13);
  int lt = slot % 13;
  int l0 = lt * 64;
  int t = threadIdx.x, w = t >> 6, lane = t & 63, g = lane >> 4, c = lane & 15;
  int lcol = l0 + 16 * w + c;

  const short* xebB = xeb + (size_t)b * MPAD * DPAD;
  const short* xTb = xeT + (size_t)b * DPAD * MPAD;

  short8 xlf[4];
  {
    const short* xrow = xebB + (size_t)lcol * DPAD + 8 * g;
#pragma unroll
    for (int ks = 0; ks < 4; ++ks)
      xlf[ks] = *reinterpret_cast<const short8*>(xrow + 32 * ks);
  }

  f32x4 pv[7];
#pragma unroll
  for (int dt = 0; dt < 7; ++dt) pv[dt] = (f32x4){0.f, 0.f, 0.f, 0.f};

  const short* aP = xebB + (size_t)c * DPAD + 8 * g;
  const short* bP = xTb + (size_t)c * MPAD + 8 * g;

  for (int mc = 0; mc < 26; ++mc) {
    int m0 = mc * 32;
    // B-frags for PV (consumed at bottom; latency hidden under scores+softmax)
    short8 bf[7];
#pragma unroll
    for (int dt = 0; dt < 7; ++dt)
      bf[dt] = *reinterpret_cast<const short8*>(bP + m0 + (size_t)dt * 16 * MPAD);

    // scores S^T[m, lcol]
    f32x4 s0 = {0.f, 0.f, 0.f, 0.f}, s1 = {0.f, 0.f, 0.f, 0.f};
    const short* a0 = aP + (size_t)m0 * DPAD;
#pragma unroll
    for (int ks = 0; ks < 4; ++ks) {
      short8 af0 = *reinterpret_cast<const short8*>(a0 + 32 * ks);
      short8 af1 = *reinterpret_cast<const short8*>(a0 + 16 * DPAD + 32 * ks);
      s0 = MFMA16(af0, xlf[ks], s0);
      s1 = MFMA16(af1, xlf[ks], s1);
    }

    // P = exp(s), diag zeroed (only 2 of 26 tiles can contain the diagonal)
    float e00 = __expf(s0[0]), e01 = __expf(s0[1]), e02 = __expf(s0[2]), e03 = __expf(s0[3]);
    float e10 = __expf(s1[0]), e11 = __expf(s1[1]), e12 = __expf(s1[2]), e13 = __expf(s1[3]);
    if ((mc >> 1) == lt) {
      int md = m0 + 4 * g;
      e00 = (md + 0 == lcol) ? 0.f : e00;
      e01 = (md + 1 == lcol) ? 0.f : e01;
      e02 = (md + 2 == lcol) ? 0.f : e02;
      e03 = (md + 3 == lcol) ? 0.f : e03;
      e10 = (md + 16 == lcol) ? 0.f : e10;
      e11 = (md + 17 == lcol) ? 0.f : e11;
      e12 = (md + 18 == lcol) ? 0.f : e12;
      e13 = (md + 19 == lcol) ? 0.f : e13;
    }
    // pack + 4x4 lane-group transpose -> PV A-frag (k = m0+8g..m0+8g+7)
    unsigned x0 = cvtpk(e00, e01), x1 = cvtpk(e02, e03);
    unsigned x2 = cvtpk(e10, e11), x3 = cvtpk(e12, e13);
    swap3216(x0, x2);
    swap3216(x1, x3);
    union { unsigned u[4]; short8 v; } pa;
    pa.u[0] = x0; pa.u[1] = x1; pa.u[2] = x2; pa.u[3] = x3;

#pragma unroll
    for (int dt = 0; dt < 7; ++dt) pv[dt] = MFMA16(pa.v, bf[dt], pv[dt]);
  }

  // epilogue: S2 = out col 100 (lane c=4), Z = out col 101 (lane c=5)
#pragma unroll
  for (int r = 0; r < 4; ++r) {
    int lrow = l0 + 16 * w + 4 * g + r;
    float S2r = __shfl(pv[6][r], 16 * g + 4);
    float Zr = __shfl(pv[6][r], 16 * g + 5) + 1.0f;  // +1: diag exp(0)
    short* xhr = xhb + ((size_t)b * MPAD + lrow) * DPAD;
    if (lrow < LL) {
      float mlr = (float)mask[b * LL + lrow];
      float inv = mlr / (mlr * S2r + Zr * 1e-13f);
      const short* xer = xebB + (size_t)lrow * DPAD;
#pragma unroll
      for (int dt = 0; dt < 7; ++dt) {
        int d = 16 * dt + c;
        xhr[d] = (d < DD) ? (short)f2bf(pv[dt][r] * inv + bf2f(xer[d])) : (short)0;
      }
      xhr[112 + c] = 0;
    } else {
#pragma unroll
      for (int dt = 0; dt < 8; ++dt) xhr[16 * dt + c] = 0;
    }
  }
}

// ---- conv as MFMA sliding GEMM: block = (b, br, 64-l tile), wave = 16-nf tile ----
template <int S>
__global__ __launch_bounds__(256) void k_convT(const short* __restrict__ xeb,
                                               const short* __restrict__ xhb,
                                               const short* __restrict__ wb,
                                               ConvP P, int* __restrict__ feat) {
  constexpr int sz = (S == 5) ? 3 : (S - 1);
  __shared__ short xt[68 * 128];
  int bid = blockIdx.x;
  int xcd = bid & 7, slot = bid >> 3;  // same batch->XCD map as attn
  int b = xcd + 8 * (slot / 26);
  int rem = slot % 26;
  int br = rem >= 13;
  int ltile = rem % 13;
  int l0 = ltile * 64;
  const short* src = (br ? xhb : xeb) + (size_t)b * MPAD * DPAD;
  int t = threadIdx.x;

  // stage 68 rows x 128 cols bf16, XOR-swizzled 16B chunks (chunk ^= row&7)
  for (int i = t; i < 68 * 16; i += 256) {
    int row = i >> 4, c16 = i & 15;
    int gr = l0 + row;
    if (gr > MPAD - 1) gr = MPAD - 1;  // rows >=800 are zero
    short8 v = *reinterpret_cast<const short8*>(src + (size_t)gr * DPAD + c16 * 8);
    *reinterpret_cast<short8*>(&xt[row * 128 + ((c16 ^ (row & 7)) << 3)]) = v;
  }
  __syncthreads();

  int w = t >> 6, lane = t & 63, g = lane >> 4, c = lane & 15;
  const short* wp = wb + ((size_t)(br * 4 + sz) * 64 + w * 16 + c) * 640 + 8 * g;
  short8 wf[S][4];
#pragma unroll
  for (int i2 = 0; i2 < S; ++i2)
#pragma unroll
    for (int ks = 0; ks < 4; ++ks)
      wf[i2][ks] = *reinterpret_cast<const short8*>(wp + i2 * 128 + 32 * ks);

  f32x4 acc[4];
#pragma unroll
  for (int u = 0; u < 4; ++u) acc[u] = (f32x4){0.f, 0.f, 0.f, 0.f};

#pragma unroll
  for (int lsub = 0; lsub < 4; ++lsub) {
#pragma unroll
    for (int i2 = 0; i2 < S; ++i2) {
      int row = lsub * 16 + c + i2;
      int rb = row * 128, rx = row & 7;
#pragma unroll
      for (int ks = 0; ks < 4; ++ks) {
        short8 af = *reinterpret_cast<const short8*>(&xt[rb + (((4 * ks + g) ^ rx) << 3)]);
        acc[lsub] = MFMA16(af, wf[i2][ks], acc[lsub]);
      }
    }
  }

  const int Lout = LL - S + 1;
  int nf = w * 16 + c;
  float bias = (nf < NFC) ? P.bias[br * 4 + sz][nf] : 0.f;
  float mx = 0.f;
#pragma unroll
  for (int lsub = 0; lsub < 4; ++lsub)
#pragma unroll
    for (int r = 0; r < 4; ++r) {
      int l = l0 + lsub * 16 + 4 * g + r;
      if (l < Lout) {
        float v = acc[lsub][r] + bias;
        mx = fmaxf(mx, v > 0.f ? v : 0.f);
      }
    }
  mx = fmaxf(mx, __shfl_xor(mx, 16));
  mx = fmaxf(mx, __shfl_xor(mx, 32));
  if (g == 0 && nf < NFC)
    atomicMax(&feat[((b * 2 + br) * 4 + sz) * NFC + nf], __float_as_int(mx));
}

// ---------------- FC + branch sum ----------------
__global__ __launch_bounds__(256) void k_fc(const float* __restrict__ feat,
                                            const float* __restrict__ fw1,
                                            const float* __restrict__ fb1,
                                            const float* __restrict__ fw2,
                                            const float* __restrict__ fb2,
                                            float* __restrict__ out) {
  int id = blockIdx.x * 256 + threadIdx.x;
  if (id >= BB * NFC) return;
  int b = id / NFC, k = id - b * NFC;
  float a = fb1[k] + fb2[k];
  const float* f1 = feat + (size_t)(b * 2 + 0) * (4 * NFC);
  const float* f2 = feat + (size_t)(b * 2 + 1) * (4 * NFC);
  const float* w1 = fw1 + k * (4 * NFC);
  const float* w2 = fw2 + k * (4 * NFC);
  for (int j = 0; j < 4 * NFC; ++j) a += f1[j] * w1[j] + f2[j] * w2[j];
  out[id] = a;
}

extern "C" void kernel_launch(void* const* d_in, const int* in_sizes, int n_in,
                              void* d_out, int out_size, void* d_ws, size_t ws_size,
                              hipStream_t stream) {
  const int* x = (const int*)d_in[0];
  const int* mask = (const int*)d_in[2];
  const float* emb = (const float*)d_in[3];
  ConvP P;
  for (int br = 0; br < 2; ++br)
    for (int j = 0; j < 4; ++j) {
      P.w[br * 4 + j] = (const float*)d_in[4 + br * 10 + j * 2];
      P.bias[br * 4 + j] = (const float*)d_in[4 + br * 10 + j * 2 + 1];
    }
  const float* fw1 = (const float*)d_in[12];
  const float* fb1 = (const float*)d_in[13];
  const float* fw2 = (const float*)d_in[22];
  const float* fb2 = (const float*)d_in[23];

  char* base = (char*)d_ws;
  short* xeb = (short*)base;                    // 13,631,488 B
  short* xeT = (short*)(base + 13631488);       // 13,631,488 B
  short* xhb = (short*)(base + 27262976);       // 13,631,488 B
  short* wb = (short*)(base + 40894464);        //    655,360 B
  int* feat = (int*)(base + 41549824);          //    102,400 B
  float* out = (float*)d_out;

  hipMemsetAsync(feat, 0, (size_t)BB * 2 * 4 * NFC * sizeof(int), stream);
  k_prep<<<BB * 13, 256, 0, stream>>>(x, emb, mask, xeb, xeT);
  k_wprep<<<(2 * 4 * 64 * 5 * 128 + 255) / 256, 256, 0, stream>>>(P, wb);
  k_attn<<<BB * 13, 256, 0, stream>>>(xeb, xeT, mask, xhb);
  k_convT<1><<<BB * 2 * 13, 256, 0, stream>>>(xeb, xhb, wb, P, feat);
  k_convT<2><<<BB * 2 * 13, 256, 0, stream>>>(xeb, xhb, wb, P, feat);
  k_convT<3><<<BB * 2 * 13, 256, 0, stream>>>(xeb, xhb, wb, P, feat);
  k_convT<5><<<BB * 2 * 13, 256, 0, stream>>>(xeb, xhb, wb, P, feat);
  k_fc<<<(BB * NFC + 255) / 256, 256, 0, stream>>>((const float*)feat, fw1, fb1,
                                                   fw2, fb2, out);
}

// Round 6
// 151.960 us; speedup vs baseline: 1.8002x; 1.8002x over previous
//
#include <hip/hip_runtime.h>
#include <hip/hip_bf16.h>

#define BB 64
#define LL 800
#define DD 100
#define NFC 50
#define MPAD 832
#define DPAD 128

typedef __attribute__((ext_vector_type(8))) short short8;
typedef __attribute__((ext_vector_type(4))) float f32x4;
#define MFMA16(a, b, c) __builtin_amdgcn_mfma_f32_16x16x32_bf16(a, b, c, 0, 0, 0)

struct ConvP {
  const float* w[8];
  const float* bias[8];
};

__device__ __forceinline__ ushort f2bf(float f) {
  unsigned u = __float_as_uint(f);
  u += 0x7fff + ((u >> 16) & 1);
  return (ushort)(u >> 16);
}
__device__ __forceinline__ float bf2f(short s) {
  return __uint_as_float(((unsigned)(ushort)s) << 16);
}
__device__ __forceinline__ unsigned cvtpk(float lo, float hi) {
  unsigned d;
  asm("v_cvt_pk_bf16_f32 %0, %1, %2" : "=v"(d) : "v"(lo), "v"(hi));
  return d;
}
__device__ __forceinline__ void swap3216(unsigned& a, unsigned& b) {
  asm("v_permlane32_swap_b32 %0, %1\n\t"
      "v_permlane16_swap_b32 %0, %1"
      : "+v"(a), "+v"(b));
}

// ---- fused gather + bf16 prep ----
// xeb[b][832][128]  : raw bf16 rows
// xeT[b][128][832]  : transposed, MASKED (d<100: x*mask; d=100: mask; d=101: 1; else 0)
__global__ __launch_bounds__(256) void k_prep(const int* __restrict__ x,
                                              const float* __restrict__ emb,
                                              const int* __restrict__ mask,
                                              short* __restrict__ xeb,
                                              short* __restrict__ xeT) {
  __shared__ float tile[64][129];
  __shared__ int toks[64];
  __shared__ float msk[64];
  int bid = blockIdx.x;
  int xcd = bid & 7, slot = bid >> 3;
  int b = xcd + 8 * (slot / 13);
  int mt = slot % 13;
  int m0 = mt * 64;
  int t = threadIdx.x;
  if (t < 64) {
    int gm = m0 + t;
    toks[t] = (gm < LL) ? x[b * LL + gm] : 1;
    msk[t] = (gm < LL) ? (float)mask[b * LL + gm] : 0.f;
  }
  __syncthreads();
  for (int i = t; i < 64 * 128; i += 256) {
    int m = i >> 7, d = i & 127;
    int gm = m0 + m;
    float v = 0.f;
    if (gm < LL && d < DD) v = emb[(size_t)toks[m] * DD + d];
    tile[m][d] = v;
    xeb[((size_t)b * MPAD + gm) * DPAD + d] = (short)f2bf(v);
  }
  __syncthreads();
  for (int i = t; i < 64 * 128; i += 256) {
    int m = i & 63, d = i >> 6;
    float mk = msk[m];
    float v;
    if (d < DD) v = tile[m][d] * mk;
    else if (d == DD) v = mk;
    else if (d == DD + 1) v = (m0 + m < LL) ? 1.f : 0.f;
    else v = 0.f;
    xeT[((size_t)b * DPAD + d) * MPAD + m0 + m] = (short)f2bf(v);
  }
}

// ---- bf16 weight pack: wb[br][sz][nf(64)][i(5)][d(128)] zero-padded ----
__global__ __launch_bounds__(256) void k_wprep(ConvP P, short* __restrict__ wb) {
  int idx = blockIdx.x * 256 + threadIdx.x;
  if (idx >= 2 * 4 * 64 * 5 * 128) return;
  int d = idx & 127;
  int r = idx >> 7;
  int i = r % 5; r /= 5;
  int nf = r & 63; r >>= 6;
  int sz = r & 3;
  int br = r >> 2;
  int s = (sz < 3) ? sz + 1 : 5;
  float v = 0.f;
  if (nf < NFC && i < s && d < DD) v = P.w[br * 4 + sz][(nf * s + i) * DD + d];
  wb[idx] = (short)f2bf(v);
}

// ---- MFMA attention: 2-phase LDS pipeline (reg-staged dbuf), permlane softmax ----
// As region: 32 rows x 136 shorts (272B stride, even banks). Bs: 112 rows x 32 shorts.
#define ASTR 136
#define BOFF (32 * ASTR)   // 4352 shorts
#define SBSZ (BOFF + 112 * 32)  // 7936 shorts per buffer
__global__ __launch_bounds__(256, 3) void k_attn(const short* __restrict__ xeb,
                                                 const short* __restrict__ xeT,
                                                 const int* __restrict__ mask,
                                                 short* __restrict__ xhb) {
  __shared__ __align__(16) short SB[2][SBSZ];
  int bid = blockIdx.x;
  int xcd = bid & 7, slot = bid >> 3;  // batch -> XCD: panels stay L2-local
  int b = xcd + 8 * (slot / 13);
  int lt = slot % 13;
  int l0 = lt * 64;
  int t = threadIdx.x, w = t >> 6, lane = t & 63, g = lane >> 4, c = lane & 15;
  int lcol = l0 + 16 * w + c;

  const short* xebB = xeb + (size_t)b * MPAD * DPAD;
  const short* xTb = xeT + (size_t)b * DPAD * MPAD;

  // per-lane staging assignment: q = p*256 + w*64 + lane
  const short* ssrc[4];
  int sdst[4], sstep[4];
  bool sval[4];
#pragma unroll
  for (int p = 0; p < 4; ++p) {
    int q = p * 256 + w * 64 + lane;
    if (q < 512) {  // As chunk: row r of 32-m tile, 16B piece j
      int r = q >> 4, j = q & 15;
      ssrc[p] = xebB + r * DPAD + j * 8;
      sstep[p] = 32 * DPAD;
      sdst[p] = r * ASTR + j * 8;
      sval[p] = true;
    } else {  // Bs chunk: row r (d-dim), 16B piece j of the 32-m slice
      int u = q - 512;
      int r = u >> 2, j = u & 3;
      ssrc[p] = xTb + r * MPAD + j * 8;
      sstep[p] = 32;
      sdst[p] = BOFF + r * 32 + j * 8;
      sval[p] = (u < 448);
    }
  }

  short8 xlf[4];
  {
    const short* xrow = xebB + (size_t)lcol * DPAD + 8 * g;
#pragma unroll
    for (int ks = 0; ks < 4; ++ks)
      xlf[ks] = *reinterpret_cast<const short8*>(xrow + 32 * ks);
  }

  f32x4 pv[7];
#pragma unroll
  for (int dt = 0; dt < 7; ++dt) pv[dt] = (f32x4){0.f, 0.f, 0.f, 0.f};

  // prologue: load chunk 0
  uint4 R[4];
#pragma unroll
  for (int p = 0; p < 4; ++p) {
    if (sval[p]) R[p] = *reinterpret_cast<const uint4*>(ssrc[p]);
    ssrc[p] += sstep[p];
  }

  int cur = 0;
  for (int mc = 0; mc < 26; ++mc) {
    int m0 = mc * 32;
    // write chunk mc to LDS (compiler inserts vmcnt wait for R)
#pragma unroll
    for (int p = 0; p < 4; ++p)
      if (sval[p]) *reinterpret_cast<short8*>(&SB[cur][sdst[p]]) =
          *reinterpret_cast<const short8*>(&R[p]);
    // issue chunk mc+1 loads (in flight across the barrier + compute)
    if (mc < 25) {
#pragma unroll
      for (int p = 0; p < 4; ++p) {
        if (sval[p]) R[p] = *reinterpret_cast<const uint4*>(ssrc[p]);
        ssrc[p] += sstep[p];
      }
    }
    asm volatile("s_waitcnt lgkmcnt(0)" ::: "memory");  // ds_writes drained
    __builtin_amdgcn_s_barrier();
    __builtin_amdgcn_sched_barrier(0);

    const short* asb = SB[cur];
    const short* bsb = SB[cur] + BOFF;

    // scores S^T[m, lcol] from LDS
    f32x4 s0 = {0.f, 0.f, 0.f, 0.f}, s1 = {0.f, 0.f, 0.f, 0.f};
#pragma unroll
    for (int ks = 0; ks < 4; ++ks) {
      short8 af0 = *reinterpret_cast<const short8*>(asb + c * ASTR + 8 * g + 32 * ks);
      short8 af1 = *reinterpret_cast<const short8*>(asb + (c + 16) * ASTR + 8 * g + 32 * ks);
      s0 = MFMA16(af0, xlf[ks], s0);
      s1 = MFMA16(af1, xlf[ks], s1);
    }

    // P = exp(s), diag zeroed (only tiles (mc>>1)==lt contain the diagonal)
    float e00 = __expf(s0[0]), e01 = __expf(s0[1]), e02 = __expf(s0[2]), e03 = __expf(s0[3]);
    float e10 = __expf(s1[0]), e11 = __expf(s1[1]), e12 = __expf(s1[2]), e13 = __expf(s1[3]);
    if ((mc >> 1) == lt) {
      int md = m0 + 4 * g;
      e00 = (md + 0 == lcol) ? 0.f : e00;
      e01 = (md + 1 == lcol) ? 0.f : e01;
      e02 = (md + 2 == lcol) ? 0.f : e02;
      e03 = (md + 3 == lcol) ? 0.f : e03;
      e10 = (md + 16 == lcol) ? 0.f : e10;
      e11 = (md + 17 == lcol) ? 0.f : e11;
      e12 = (md + 18 == lcol) ? 0.f : e12;
      e13 = (md + 19 == lcol) ? 0.f : e13;
    }
    unsigned x0 = cvtpk(e00, e01), x1 = cvtpk(e02, e03);
    unsigned x2 = cvtpk(e10, e11), x3 = cvtpk(e12, e13);
    swap3216(x0, x2);
    swap3216(x1, x3);
    union { unsigned u[4]; short8 v; } pa;
    pa.u[0] = x0; pa.u[1] = x1; pa.u[2] = x2; pa.u[3] = x3;

    // PV from LDS B-frags
#pragma unroll
    for (int dt = 0; dt < 7; ++dt) {
      short8 bf = *reinterpret_cast<const short8*>(bsb + (c + 16 * dt) * 32 + 8 * g);
      pv[dt] = MFMA16(pa.v, bf, pv[dt]);
    }
    cur ^= 1;
  }

  // epilogue: S2 = out col 100 (lane c=4), Z = out col 101 (lane c=5)
#pragma unroll
  for (int r = 0; r < 4; ++r) {
    int lrow = l0 + 16 * w + 4 * g + r;
    float S2r = __shfl(pv[6][r], 16 * g + 4);
    float Zr = __shfl(pv[6][r], 16 * g + 5) + 1.0f;  // +1: diag exp(0)
    short* xhr = xhb + ((size_t)b * MPAD + lrow) * DPAD;
    if (lrow < LL) {
      float mlr = (float)mask[b * LL + lrow];
      float inv = mlr / (mlr * S2r + Zr * 1e-13f);
      const short* xer = xebB + (size_t)lrow * DPAD;
#pragma unroll
      for (int dt = 0; dt < 7; ++dt) {
        int d = 16 * dt + c;
        xhr[d] = (d < DD) ? (short)f2bf(pv[dt][r] * inv + bf2f(xer[d])) : (short)0;
      }
      xhr[112 + c] = 0;
    } else {
#pragma unroll
      for (int dt = 0; dt < 8; ++dt) xhr[16 * dt + c] = 0;
    }
  }
}

// ---- merged conv: stage x-tile once, run all 4 sizes; MFMA sliding GEMM ----
template <int S>
__device__ __forceinline__ void conv_piece(const short* xt, const short* __restrict__ wb,
                                           const ConvP& P, int* __restrict__ feat,
                                           int b, int br, int l0, int w, int g, int c) {
  constexpr int sz = (S == 5) ? 3 : (S - 1);
  const short* wp = wb + ((size_t)(br * 4 + sz) * 64 + w * 16 + c) * 640 + 8 * g;
  short8 wf[S][4];
#pragma unroll
  for (int i2 = 0; i2 < S; ++i2)
#pragma unroll
    for (int ks = 0; ks < 4; ++ks)
      wf[i2][ks] = *reinterpret_cast<const short8*>(wp + i2 * 128 + 32 * ks);

  f32x4 acc[4];
#pragma unroll
  for (int u = 0; u < 4; ++u) acc[u] = (f32x4){0.f, 0.f, 0.f, 0.f};

#pragma unroll
  for (int lsub = 0; lsub < 4; ++lsub) {
#pragma unroll
    for (int i2 = 0; i2 < S; ++i2) {
      int row = lsub * 16 + c + i2;
      int rb = row * 128, rx = row & 7;
#pragma unroll
      for (int ks = 0; ks < 4; ++ks) {
        short8 af = *reinterpret_cast<const short8*>(&xt[rb + (((4 * ks + g) ^ rx) << 3)]);
        acc[lsub] = MFMA16(af, wf[i2][ks], acc[lsub]);
      }
    }
  }

  const int Lout = LL - S + 1;
  int nf = w * 16 + c;
  float bias = (nf < NFC) ? P.bias[br * 4 + sz][nf] : 0.f;
  float mx = 0.f;
#pragma unroll
  for (int lsub = 0; lsub < 4; ++lsub)
#pragma unroll
    for (int r = 0; r < 4; ++r) {
      int l = l0 + lsub * 16 + 4 * g + r;
      if (l < Lout) {
        float v = acc[lsub][r] + bias;
        mx = fmaxf(mx, v > 0.f ? v : 0.f);
      }
    }
  mx = fmaxf(mx, __shfl_xor(mx, 16));
  mx = fmaxf(mx, __shfl_xor(mx, 32));
  if (g == 0 && nf < NFC)
    atomicMax(&feat[((b * 2 + br) * 4 + sz) * NFC + nf], __float_as_int(mx));
}

__global__ __launch_bounds__(256) void k_conv(const short* __restrict__ xeb,
                                              const short* __restrict__ xhb,
                                              const short* __restrict__ wb,
                                              ConvP P, int* __restrict__ feat) {
  __shared__ __align__(16) short xt[68 * 128];
  int bid = blockIdx.x;
  int xcd = bid & 7, slot = bid >> 3;
  int b = xcd + 8 * (slot / 26);
  int rem = slot % 26;
  int br = rem >= 13;
  int ltile = rem % 13;
  int l0 = ltile * 64;
  const short* src = (br ? xhb : xeb) + (size_t)b * MPAD * DPAD;
  int t = threadIdx.x;

  for (int i = t; i < 68 * 16; i += 256) {
    int row = i >> 4, c16 = i & 15;
    int gr = l0 + row;
    if (gr > MPAD - 1) gr = MPAD - 1;  // rows >=800 are zero
    short8 v = *reinterpret_cast<const short8*>(src + (size_t)gr * DPAD + c16 * 8);
    *reinterpret_cast<short8*>(&xt[row * 128 + ((c16 ^ (row & 7)) << 3)]) = v;
  }
  __syncthreads();

  int w = t >> 6, lane = t & 63, g = lane >> 4, c = lane & 15;
  conv_piece<1>(xt, wb, P, feat, b, br, l0, w, g, c);
  conv_piece<2>(xt, wb, P, feat, b, br, l0, w, g, c);
  conv_piece<3>(xt, wb, P, feat, b, br, l0, w, g, c);
  conv_piece<5>(xt, wb, P, feat, b, br, l0, w, g, c);
}

// ---------------- FC + branch sum ----------------
__global__ __launch_bounds__(256) void k_fc(const float* __restrict__ feat,
                                            const float* __restrict__ fw1,
                                            const float* __restrict__ fb1,
                                            const float* __restrict__ fw2,
                                            const float* __restrict__ fb2,
                                            float* __restrict__ out) {
  int id = blockIdx.x * 256 + threadIdx.x;
  if (id >= BB * NFC) return;
  int b = id / NFC, k = id - b * NFC;
  float a = fb1[k] + fb2[k];
  const float* f1 = feat + (size_t)(b * 2 + 0) * (4 * NFC);
  const float* f2 = feat + (size_t)(b * 2 + 1) * (4 * NFC);
  const float* w1 = fw1 + k * (4 * NFC);
  const float* w2 = fw2 + k * (4 * NFC);
  for (int j = 0; j < 4 * NFC; ++j) a += f1[j] * w1[j] + f2[j] * w2[j];
  out[id] = a;
}

extern "C" void kernel_launch(void* const* d_in, const int* in_sizes, int n_in,
                              void* d_out, int out_size, void* d_ws, size_t ws_size,
                              hipStream_t stream) {
  const int* x = (const int*)d_in[0];
  const int* mask = (const int*)d_in[2];
  const float* emb = (const float*)d_in[3];
  ConvP P;
  for (int br = 0; br < 2; ++br)
    for (int j = 0; j < 4; ++j) {
      P.w[br * 4 + j] = (const float*)d_in[4 + br * 10 + j * 2];
      P.bias[br * 4 + j] = (const float*)d_in[4 + br * 10 + j * 2 + 1];
    }
  const float* fw1 = (const float*)d_in[12];
  const float* fb1 = (const float*)d_in[13];
  const float* fw2 = (const float*)d_in[22];
  const float* fb2 = (const float*)d_in[23];

  char* base = (char*)d_ws;
  short* xeb = (short*)base;                    // 13,631,488 B
  short* xeT = (short*)(base + 13631488);       // 13,631,488 B
  short* xhb = (short*)(base + 27262976);       // 13,631,488 B
  short* wb = (short*)(base + 40894464);        //    655,360 B
  int* feat = (int*)(base + 41549824);          //    102,400 B
  float* out = (float*)d_out;

  hipMemsetAsync(feat, 0, (size_t)BB * 2 * 4 * NFC * sizeof(int), stream);
  k_prep<<<BB * 13, 256, 0, stream>>>(x, emb, mask, xeb, xeT);
  k_wprep<<<(2 * 4 * 64 * 5 * 128 + 255) / 256, 256, 0, stream>>>(P, wb);
  k_attn<<<BB * 13, 256, 0, stream>>>(xeb, xeT, mask, xhb);
  k_conv<<<BB * 2 * 13, 256, 0, stream>>>(xeb, xhb, wb, P, feat);
  k_fc<<<(BB * NFC + 255) / 256, 256, 0, stream>>>((const float*)feat, fw1, fb1,
                                                   fw2, fb2, out);
}